// Round 14
// baseline (135.689 us; speedup 1.0000x reference)
//
#include <hip/hip_runtime.h>
#include <math.h>

// Problem dims (from reference): B=4, C=64, T=16, H=128, W=128, fp32.
#define BB 4
#define CC 64
#define TT 16
#define HH 128
#define WW 128
#define HW (HH*WW)

typedef float f32x4 __attribute__((ext_vector_type(4)));

__device__ __forceinline__ float softplus_f(float x) {
    return (x > 20.0f) ? x : log1pf(expf(x));
}

__device__ __forceinline__ float4 splat4(float v) { return make_float4(v, v, v, v); }

// float4 cross-lane fetch within a 32-lane row segment (ds_bpermute x4).
// Out-of-range src wraps (&31) -> caller masks those lanes with a select.
__device__ __forceinline__ float4 shfl4(float4 v, int src) {
    float4 r;
    r.x = __shfl(v.x, src, 32);
    r.y = __shfl(v.y, src, 32);
    r.z = __shfl(v.z, src, 32);
    r.w = __shfl(v.w, src, 32);
    return r;
}

// Best-of-both: round-11's BLOCK footprint (1024 blocks, 32-row bands ->
// 1024 L3 streams, FETCH 164 MB sweet spot) + round-12's THREAD granularity
// (2-row threads -> VGPR 64, no spill). 1024 blocks x 512 threads: same
// band per block as round 11, covered by 16 row-pairs x 32 lanes. At VGPR
// 64 all 4 resident blocks' 32 waves fit per CU (8 waves/SIMD x 64 = 512)
// -> 2x round-11's latency hiding with IDENTICAL DRAM/L3 behavior.
// Round-12 failure was 2048 block streams thrashing L3 (FETCH 326 MB);
// round-13 failure was cross-plane prefetch widening the L3 window
// (FETCH 220 MB, VGPR 104). This changes neither.
//  - NO LDS, NO barriers, NO prefetch: waves free-run
//  - horizontal taps via lane shuffles (round 11 win)
//  - vertical d=1 taps from own registers; d=4,16 clamped cache loads
//  - temporal history (t-1, t-2) in registers
//  - plain __launch_bounds__(512): ",N" variants pinned VGPR and spilled
__global__ __launch_bounds__(512) void lap_st_kernel(
    const float* __restrict__ u,
    const float* __restrict__ Ds,   // (3, 64)
    const float* __restrict__ Dt,   // (2, 64)
    float* __restrict__ out)
{
    const int bid  = blockIdx.x;
    const int sh   = bid >> 8;             // 0..3 : 32-row band
    const int bc   = bid & 255;            // b*C + c
    const int c    = bc & (CC - 1);
    const int tid  = threadIdx.x;
    const int jj   = tid >> 5;             // 0..15 : row pair within band
    const int colc = tid & 31;             // chunk column (lane in row segment)
    const int col  = colc << 2;
    const int r0   = (sh << 5) + (jj << 1); // first of 2 owned rows, 0..126

    const float cs0 = softplus_f(Ds[0 * CC + c]);
    const float cs1 = softplus_f(Ds[1 * CC + c]);
    const float cs2 = softplus_f(Ds[2 * CC + c]);
    const float ct0 = softplus_f(Dt[0 * CC + c]);
    const float ct1 = softplus_f(Dt[1 * CC + c]);
    const float cu = -4.0f * (cs0 + cs1 + cs2) - (ct0 + ct1);

    const size_t bc_off = (size_t)bc * TT * HW;

    float4 pm1[2], pm2[2];

    #pragma unroll 1
    for (int t = 0; t < TT; ++t) {
        const float* __restrict__ up = u + bc_off + (size_t)t * HW;
        f32x4* outp = (f32x4*)(out + bc_off + (size_t)t * HW);

        // center rows (registers; feed d=1 taps, horizontals via shuffle,
        // and the temporal rotate)
        float4 c0[2];
        #pragma unroll
        for (int q = 0; q < 2; ++q)
            c0[q] = *(const float4*)(up + (r0 + q) * WW + col);

        if (t == 0) {   // causal clamp: u[-1] = u[-2] = u[0]
            #pragma unroll
            for (int q = 0; q < 2; ++q) { pm1[q] = c0[q]; pm2[q] = c0[q]; }
        }

        // boundary rows for +-1 taps at the pair edges
        const int rm1 = (r0 - 1 < 0) ? 0 : r0 - 1;
        const int rp2 = (r0 + 2 > HH - 1) ? HH - 1 : r0 + 2;
        const float4 vm1 = *(const float4*)(up + rm1 * WW + col);
        const float4 vp2 = *(const float4*)(up + rp2 * WW + col);

        #pragma unroll
        for (int q = 0; q < 2; ++q) {
            const int r = r0 + q;

            // ---- vertical taps (d=1 from registers; d=4,16 clamped loads) ----
            const float4 vu1 = (q == 0) ? vm1 : c0[0];
            const float4 vd1 = (q == 1) ? vp2 : c0[1];
            int ru4 = r - 4;  ru4 = ru4 < 0 ? 0 : ru4;
            int rd4 = r + 4;  rd4 = rd4 > HH - 1 ? HH - 1 : rd4;
            int ru16 = r - 16; ru16 = ru16 < 0 ? 0 : ru16;
            int rd16 = r + 16; rd16 = rd16 > HH - 1 ? HH - 1 : rd16;
            const float4 vu4  = *(const float4*)(up + ru4  * WW + col);
            const float4 vd4  = *(const float4*)(up + rd4  * WW + col);
            const float4 vu16 = *(const float4*)(up + ru16 * WW + col);
            const float4 vd16 = *(const float4*)(up + rd16 * WW + col);

            const float4 cc = c0[q];

            // ---- horizontal taps from adjacent lanes' registers ----
            const float4 L4  = shfl4(cc, colc - 1);
            const float4 R4  = shfl4(cc, colc + 1);
            const float4 L16 = shfl4(cc, colc - 4);
            const float4 R16 = shfl4(cc, colc + 4);
            const float e0   = __shfl(cc.x, 0, 32);    // row elem 0
            const float e127 = __shfl(cc.w, 31, 32);   // row elem 127
            const float4 l4  = (colc >= 1)  ? L4  : splat4(e0);
            const float4 r4  = (colc <= 30) ? R4  : splat4(e127);
            const float4 l16 = (colc >= 4)  ? L16 : splat4(e0);
            const float4 r16 = (colc <= 27) ? R16 : splat4(e127);

            const float4 p1 = pm1[q];
            const float4 p2 = pm2[q];

            f32x4 o;
            o.x = cs0 * (vu1.x + vd1.x + l4.w + cc.y)
                + cs1 * (vu4.x + vd4.x + l4.x + r4.x)
                + cs2 * (vu16.x + vd16.x + l16.x + r16.x)
                + cu * cc.x + ct0 * p1.x + ct1 * p2.x;
            o.y = cs0 * (vu1.y + vd1.y + cc.x + cc.z)
                + cs1 * (vu4.y + vd4.y + l4.y + r4.y)
                + cs2 * (vu16.y + vd16.y + l16.y + r16.y)
                + cu * cc.y + ct0 * p1.y + ct1 * p2.y;
            o.z = cs0 * (vu1.z + vd1.z + cc.y + cc.w)
                + cs1 * (vu4.z + vd4.z + l4.z + r4.z)
                + cs2 * (vu16.z + vd16.z + l16.z + r16.z)
                + cu * cc.z + ct0 * p1.z + ct1 * p2.z;
            o.w = cs0 * (vu1.w + vd1.w + cc.z + r4.x)
                + cs1 * (vu4.w + vd4.w + l4.w + r4.w)
                + cs2 * (vu16.w + vd16.w + l16.w + r16.w)
                + cu * cc.w + ct0 * p1.w + ct1 * p2.w;

            __builtin_nontemporal_store(o, &outp[r * 32 + colc]);
        }

        // rotate temporal history
        #pragma unroll
        for (int q = 0; q < 2; ++q) { pm2[q] = pm1[q]; pm1[q] = c0[q]; }
    }
}

extern "C" void kernel_launch(void* const* d_in, const int* in_sizes, int n_in,
                              void* d_out, int out_size, void* d_ws, size_t ws_size,
                              hipStream_t stream) {
    const float* u  = (const float*)d_in[0];
    const float* Ds = (const float*)d_in[1];
    const float* Dt = (const float*)d_in[2];
    float* out = (float*)d_out;

    const int nblocks = 4 * BB * CC;   // 1024 blocks = 4 per CU, 512 thr each
    lap_st_kernel<<<dim3(nblocks), dim3(512), 0, stream>>>(u, Ds, Dt, out);
}